// Round 10
// baseline (385.816 us; speedup 1.0000x reference)
//
#include <hip/hip_runtime.h>
#include <hip/hip_bf16.h>

// MoE SwiGLU MLP, sparse top-2 path.
// T=2048 tokens, D_MODEL=1024, D_FF=2048, E=8 experts, K=2.
// R8 349.0 / R13 350.9 (equal best): prep hidden under router+gu; gu pinned at
//     94us over 3 designs — 238MB @ 2.53 TB/s delivered, MfmaUtil 15%,
//     the 2-barrier vmcnt(0)-drain wall. fp32-direct weights ruled out (R9/R12).
//     __syncthreads-based "pipelining" ruled out (R11 — it drains vmcnt).
// R14: counted-vmcnt 2-phase in gu (T3/T4 recipe): raw s_barrier + explicit
//     s_waitcnt vmcnt(12) (never 0 in steady state). Per-iter ledger/thread:
//     A-load 4 (reg-staged; compiler reg-dep wait leaves B flying) + B-stage 8
//     glds16 dbuf. As 16KB linear XOR-swizzled (write & read) — T2 gate: with
//     stage stall removed, LDS reads become critical. LDS 80KB = 2 blocks/CU.
//     Predict gu 94 -> 68-78us, MfmaUtil -> 20-26%, total -> ~320-330us.

#define D_MODEL 1024
#define D_FF    2048
#define N_EXP   8
#define T_TOK   2048
#define MAXTILES 40   // 128-row tiles: sum_e ceil(cnt_e/128) <= 32+7 < 40
#define MAXT64   80   // 64-row tiles:  sum_e ceil(cnt_e/64)  <= 64+8 < 80

typedef __attribute__((ext_vector_type(8))) short bf16x8;
typedef __attribute__((ext_vector_type(8))) ushort u16x8;
typedef __attribute__((ext_vector_type(4))) float f32x4;

__device__ __forceinline__ ushort f2bf(float f) {
    union { float f; unsigned u; } c; c.f = f;
    unsigned u = c.u;
    return (ushort)((u + 0x7fffu + ((u >> 16) & 1u)) >> 16);  // RTNE
}

__device__ __forceinline__ void glds16(const void* g, void* l) {
    __builtin_amdgcn_global_load_lds(
        (const __attribute__((address_space(1))) unsigned int*)g,
        (__attribute__((address_space(3))) unsigned int*)l, 16, 0, 0);
}

// ---------------- prep helpers: fp32 -> bf16, tiled k-inner-8 (verified R6/R8) ----------------
__device__ __forceinline__ void prep_slab_gwu(
    int sp, int tid, const float* __restrict__ Wg, const float* __restrict__ Wu,
    ushort* __restrict__ Wgt, ushort* __restrict__ Wut, ushort* lds)
{
    int which = sp >> 10, s = sp & 1023;
    const float* src = which ? Wu : Wg;
    ushort* dst = which ? Wut : Wgt;
    int e = s >> 7, kt = (s >> 3) & 15, kb = s & 7;
    const float4* p = (const float4*)(src + (size_t)e * 1024 * 2048 + (size_t)(kt * 64 + kb * 8) * 2048);
#pragma unroll
    for (int i = 0; i < 16; i++) {
        float4 v = p[i * 256 + tid];
        ushort4 o;
        o.x = f2bf(v.x); o.y = f2bf(v.y); o.z = f2bf(v.z); o.w = f2bf(v.w);
        *(ushort4*)&lds[(i * 256 + tid) * 4] = o;
    }
    __syncthreads();
    u16x8 in[8];
#pragma unroll
    for (int ko = 0; ko < 8; ko++)
        in[ko] = *(const u16x8*)&lds[ko * 2048 + tid * 8];
    u16x8 out[8];
#pragma unroll
    for (int j = 0; j < 8; j++)
#pragma unroll
        for (int ko = 0; ko < 8; ko++)
            out[j][ko] = in[ko][j];
    __syncthreads();
    int swz = (tid & 7) << 4;
#pragma unroll
    for (int j = 0; j < 8; j++)
        *(u16x8*)((char*)lds + (((8 * tid + j) * 16) ^ swz)) = out[j];
    __syncthreads();
#pragma unroll
    for (int i = 0; i < 8; i++) {
        int c = i * 256 + tid;
        u16x8 v = *(const u16x8*)((char*)lds + ((c * 16) ^ (((c >> 3) & 7) << 4)));
        int R = c >> 7, q = c & 127;
        *(u16x8*)&dst[(size_t)(e * 256 + R * 16 + kt) * 8192 + kb * 1024 + q * 8] = v;
    }
}

__device__ __forceinline__ void prep_slab_wd(
    int s, int tid, const float* __restrict__ Wd, ushort* __restrict__ Wdt, ushort* lds)
{
    int e = s >> 7, kt = (s >> 2) & 31, kbp = s & 3;
    const float4* p = (const float4*)(Wd + (size_t)e * 2048 * 1024 + (size_t)(kt * 64 + kbp * 16) * 1024);
#pragma unroll
    for (int i = 0; i < 16; i++) {
        float4 v = p[i * 256 + tid];
        ushort4 o;
        o.x = f2bf(v.x); o.y = f2bf(v.y); o.z = f2bf(v.z); o.w = f2bf(v.w);
        *(ushort4*)&lds[(i * 256 + tid) * 4] = o;
    }
    __syncthreads();
    u16x8 in[8];
    int th = tid >> 7, tc = tid & 127;
#pragma unroll
    for (int ko = 0; ko < 8; ko++)
        in[ko] = *(const u16x8*)&lds[(th * 8 + ko) * 1024 + tc * 8];
    u16x8 out[8];
#pragma unroll
    for (int j = 0; j < 8; j++)
#pragma unroll
        for (int ko = 0; ko < 8; ko++)
            out[j][ko] = in[ko][j];
    __syncthreads();
    int swz = (tid & 7) << 4;
#pragma unroll
    for (int j = 0; j < 8; j++)
        *(u16x8*)((char*)lds + (((8 * tid + j) * 16) ^ swz)) = out[j];
    __syncthreads();
#pragma unroll
    for (int i = 0; i < 8; i++) {
        int c = i * 256 + tid;
        u16x8 v = *(const u16x8*)((char*)lds + ((c * 16) ^ (((c >> 3) & 7) << 4)));
        int R = c >> 7, q = c & 127;
        int kb2 = R >> 3, ntp = R & 7;
        *(u16x8*)&Wdt[(size_t)(e * 256 + ntp * 32 + kt) * 8192 + (kbp * 2 + kb2) * 1024 + q * 8] = v;
    }
}

// ---------------- launch 1: router (blocks 0..63) + Wg/Wu prep (64..2111) ----------------
union SM1 {
    float gws[N_EXP * D_MODEL];   // 32 KB router gate-weight cache
    ushort prep[16384];           // 32 KB prep scratch
};

__global__ __launch_bounds__(256) void k_router_prep(
    const float* __restrict__ x, const float* __restrict__ gw, const float* __restrict__ gb,
    int* cnt, float* probsum, int* tok, int* slotpk, float* wtok,
    ushort* __restrict__ xb,
    const float* __restrict__ Wg, const float* __restrict__ Wu,
    ushort* __restrict__ Wgt, ushort* __restrict__ Wut)
{
    __shared__ __align__(16) SM1 smem;
    __shared__ float ps_s[N_EXP];
    __shared__ int   bc_s[N_EXP];
    __shared__ int   gb_s[N_EXP];
    __shared__ int   a_e[64];
    __shared__ int   a_lp[64];

    int tid = threadIdx.x;
    int bid = blockIdx.x;

    if (bid >= 64) {                      // ---- prep role ----
        prep_slab_gwu(bid - 64, tid, Wg, Wu, Wgt, Wut, smem.prep);
        return;
    }

    // ---- router role ----
    float* gws = smem.gws;
    for (int i = tid; i < N_EXP * D_MODEL / 4; i += 256)
        ((float4*)gws)[i] = ((const float4*)gw)[i];
    if (tid < N_EXP) { ps_s[tid] = 0.f; bc_s[tid] = 0; }
    __syncthreads();

    int wave = tid >> 6, lane = tid & 63;

    for (int it = 0; it < 8; it++) {
        int tb = it * 4 + wave;                      // token-in-block
        int t = bid * 32 + tb;
        const float4* xr = (const float4*)(x + (size_t)t * D_MODEL);
        ushort* xbr = xb + (size_t)t * D_MODEL;

        float acc[N_EXP];
#pragma unroll
        for (int e = 0; e < N_EXP; e++) acc[e] = 0.f;
#pragma unroll
        for (int q = 0; q < 4; q++) {
            int idx = q * 64 + lane;
            float4 xv = xr[idx];
            ushort4 xc;
            xc.x = f2bf(xv.x); xc.y = f2bf(xv.y); xc.z = f2bf(xv.z); xc.w = f2bf(xv.w);
            *(ushort4*)&xbr[idx * 4] = xc;
#pragma unroll
            for (int e = 0; e < N_EXP; e++) {
                float4 gv = ((const float4*)(gws + e * D_MODEL))[idx];
                acc[e] += xv.x * gv.x + xv.y * gv.y + xv.z * gv.z + xv.w * gv.w;
            }
        }
#pragma unroll
        for (int off = 32; off > 0; off >>= 1) {
#pragma unroll
            for (int e = 0; e < N_EXP; e++) acc[e] += __shfl_xor(acc[e], off, 64);
        }
        if (lane == 0) {
            float l[N_EXP], m = -1e30f;
#pragma unroll
            for (int e = 0; e < N_EXP; e++) { l[e] = acc[e] + gb[e]; m = fmaxf(m, l[e]); }
            float p[N_EXP], s = 0.f;
#pragma unroll
            for (int e = 0; e < N_EXP; e++) { p[e] = expf(l[e] - m); s += p[e]; }
            float inv = 1.f / s;
#pragma unroll
            for (int e = 0; e < N_EXP; e++) { p[e] *= inv; atomicAdd(&ps_s[e], p[e]); }
            // top-2, lowest index wins ties (matches lax.top_k)
            int i0 = 0; float v0 = p[0];
#pragma unroll
            for (int e = 1; e < N_EXP; e++) if (p[e] > v0) { v0 = p[e]; i0 = e; }
            int i1 = -1; float v1 = -1.f;
#pragma unroll
            for (int e = 0; e < N_EXP; e++) if (e != i0 && p[e] > v1) { v1 = p[e]; i1 = e; }
            float winv = 1.f / (v0 + v1);
            int lp0 = atomicAdd(&bc_s[i0], 1);
            int lp1 = atomicAdd(&bc_s[i1], 1);
            a_e[tb * 2 + 0] = i0; a_lp[tb * 2 + 0] = lp0;
            a_e[tb * 2 + 1] = i1; a_lp[tb * 2 + 1] = lp1;
            wtok[t * 2 + 0] = v0 * winv;
            wtok[t * 2 + 1] = v1 * winv;
        }
    }
    __syncthreads();
    if (tid < N_EXP) {
        gb_s[tid] = atomicAdd(&cnt[tid], bc_s[tid]);
        atomicAdd(&probsum[tid], ps_s[tid]);
    }
    __syncthreads();
    if (tid < 64) {
        int tb = tid >> 1, k = tid & 1;
        int t = bid * 32 + tb;
        int e = a_e[tid];
        int slot = gb_s[e] + a_lp[tid];
        tok[e * T_TOK + slot] = t;
        slotpk[t * 2 + k] = (e << 16) | slot;
    }
}

// ---------------- 128-aligned expert bases + tile tables + balance loss ----------------
__global__ void k_base_loss(const int* __restrict__ cnt, const float* __restrict__ probsum,
                            int* abase, int* tile, int* tile64, float* loss_out)
{
    if (threadIdx.x == 0 && blockIdx.x == 0) {
        int b = 0, nt = 0, n64 = 0;
        float loss = 0.f;
        for (int e = 0; e < N_EXP; e++) {
            abase[e] = b;
            for (int m0 = 0; m0 < cnt[e]; m0 += 128)
                tile[nt++] = (e << 16) | m0;
            for (int m0 = 0; m0 < cnt[e]; m0 += 64)
                tile64[n64++] = (e << 16) | m0;
            b += ((cnt[e] + 127) >> 7) * 128;           // capacity-aligned
            float mean = probsum[e] * (1.0f / T_TOK);
            loss += 0.125f * (logf(0.125f) - logf(mean + 1e-9f));
        }
        for (; nt < MAXTILES; nt++) tile[nt] = -1;
        for (; n64 < MAXT64; n64++) tile64[n64] = -1;
        *loss_out = loss;
    }
}

// ---------------- launch 3: counted-vmcnt gu-GEMM (0..639) + Wd prep (640..1663) ----------------
// As: 16KB linear [128 rows][64 k] bf16, XOR-swizzled: (row,koct) stored at
//     ushort idx row*64 + ((koct ^ (row&7))*8). Reg-staged ds_write_b128.
// Bg/Bu: k-inner-8 16KB images, double-buffered via glds16.
// Per-iter vmem ledger/thread: A-load 4 + B-stage 8. Steady-state wait = vmcnt(12).
struct SM_GU {
    ushort As[8192];                 // 16 KB
    ushort Bg0[8192], Bg1[8192];     // 32 KB
    ushort Bu0[8192], Bu1[8192];     // 32 KB
};                                    // 80 KB total
union SM3 {
    SM_GU g;
    ushort prep[16384]; // 32 KB prep scratch
};

__global__ __launch_bounds__(256, 2) void k_gu_prepwd(
    const ushort* __restrict__ Wgt, const ushort* __restrict__ Wut,
    const float* __restrict__ bg, const float* __restrict__ bu,
    const ushort* __restrict__ xb, const int* __restrict__ cnt,
    const int* __restrict__ abase, const int* __restrict__ tile,
    const int* __restrict__ tok, ushort* __restrict__ h_t,
    const float* __restrict__ Wd, ushort* __restrict__ Wdt)
{
    __shared__ __align__(16) SM3 smem;

    int bid = blockIdx.x;
    int tid = threadIdx.x;

    if (bid >= MAXTILES * 16) {           // ---- prep-Wd role ----
        prep_slab_wd(bid - MAXTILES * 16, tid, Wd, Wdt, smem.prep);
        return;
    }

    // ---- gu GEMM role ----
    int ti = tile[bid % MAXTILES];
    if (ti < 0) return;
    int e = ti >> 16, m0 = ti & 0xffff;
    int ne = cnt[e];
    int nt = bid / MAXTILES;                  // 0..15
    int n0 = nt * 128;
    int stile = (abase[e] >> 7) + (m0 >> 7);

    ushort* As   = smem.g.As;
    ushort* Bg0  = smem.g.Bg0; ushort* Bg1 = smem.g.Bg1;
    ushort* Bu0  = smem.g.Bu0; ushort* Bu1 = smem.g.Bu1;

    int lane = tid & 63, wave = tid >> 6;
    int wm = (wave & 1) * 64, wn = (wave >> 1) * 64;

    // A: one gathered row per 2 threads (R8 mapping), swizzled ds_write dests
    int arow = tid >> 1;
    int akh = (tid & 1) * 32;                 // ushort offset of k-half
    int atok = tok[e * T_TOK + min(m0 + arow, ne - 1)];
    const ushort* xrow = xb + (size_t)atok * D_MODEL;
    int adst[4];
#pragma unroll
    for (int q = 0; q < 4; q++) {
        int koct = (tid & 1) * 4 + q;
        adst[q] = arow * 64 + ((koct ^ (arow & 7)) * 8);
    }

    const char* gbase = (const char*)(Wgt + (size_t)(e * 16 + nt) * 16 * 8192);
    const char* ubase = (const char*)(Wut + (size_t)(e * 16 + nt) * 16 * 8192);
    int goff = tid * 16;
    int loff = (tid >> 6) * 1024;

    f32x4 accg[4][4], accu[4][4];
#pragma unroll
    for (int i = 0; i < 4; i++)
#pragma unroll
        for (int j = 0; j < 4; j++) {
            accg[i][j] = (f32x4){0.f, 0.f, 0.f, 0.f};
            accu[i][j] = (f32x4){0.f, 0.f, 0.f, 0.f};
        }

    // prologue: A(0) loads into regs; B(0) staged into buf0
    uint4 a_regs[4];
#pragma unroll
    for (int q = 0; q < 4; q++)
        a_regs[q] = *(const uint4*)&xrow[akh + q * 8];
#pragma unroll
    for (int q = 0; q < 4; q++) {
        glds16(gbase + q * 4096 + goff, (char*)Bg0 + q * 4096 + loff);
        glds16(ubase + q * 4096 + goff, (char*)Bu0 + q * 4096 + loff);
    }

    ushort* Bgc = Bg0; ushort* Bgn = Bg1;
    ushort* Buc = Bu0; ushort* Bun = Bu1;

    for (int kt = 0; kt < 16; kt++) {
        // 1. As(kt) from regs (swizzled ds_write; compiler waits a_regs via reg-dep,
        //    leaving B(kt) glds16 in flight)
#pragma unroll
        for (int q = 0; q < 4; q++)
            *(uint4*)&As[adst[q]] = a_regs[q];
        if (kt < 15) {
            // 2. A(kt+1) loads (4 vmem)
#pragma unroll
            for (int q = 0; q < 4; q++)
                a_regs[q] = *(const uint4*)&xrow[(kt + 1) * 64 + akh + q * 8];
            // 3. B(kt+1) stage into other buffer (8 vmem)
            const char* gsrc = gbase + (kt + 1) * 16384;
            const char* usrc = ubase + (kt + 1) * 16384;
#pragma unroll
            for (int q = 0; q < 4; q++) {
                glds16(gsrc + q * 4096 + goff, (char*)Bgn + q * 4096 + loff);
                glds16(usrc + q * 4096 + goff, (char*)Bun + q * 4096 + loff);
            }
            // 4. counted wait: B(kt) retired; A(kt+1)+B(kt+1)=12 stay in flight
            asm volatile("s_waitcnt vmcnt(12) lgkmcnt(0)" ::: "memory");
        } else {
            asm volatile("s_waitcnt vmcnt(0) lgkmcnt(0)" ::: "memory");
        }
        __builtin_amdgcn_s_barrier();
        __builtin_amdgcn_sched_barrier(0);
        // 5. MFMA on As + Bc
#pragma unroll
        for (int ks = 0; ks < 2; ks++) {
            bf16x8 af[4];
            int r0 = wm + (lane & 15);
            int koct = ks * 4 + (lane >> 4);
#pragma unroll
            for (int sm_ = 0; sm_ < 4; sm_++) {
                int r = r0 + sm_ * 16;
                af[sm_] = *(const bf16x8*)&As[r * 64 + ((koct ^ (r & 7)) * 8)];
            }
            int bkb = ks * 4 + (lane >> 4);
#pragma unroll
            for (int sn = 0; sn < 4; sn++) {
                int ncol = wn + sn * 16 + (lane & 15);
                bf16x8 bgf = *(const bf16x8*)&Bgc[(bkb * 128 + ncol) * 8];
                bf16x8 buf = *(const bf16x8*)&Buc[(bkb * 128 + ncol) * 8];
#pragma unroll
                for (int sm_ = 0; sm_ < 4; sm_++) {
                    accg[sm_][sn] = __builtin_amdgcn_mfma_f32_16x16x32_bf16(af[sm_], bgf, accg[sm_][sn], 0, 0, 0);
                    accu[sm_][sn] = __builtin_amdgcn_mfma_f32_16x16x32_bf16(af[sm_], buf, accu[sm_][sn], 0, 0, 0);
                }
            }
        }
        // 6. all waves done reading As(kt)/Bc(kt) before overwrite next iter
        if (kt < 15) __builtin_amdgcn_s_barrier();
        // swap B buffers
        ushort* t1 = Bgc; Bgc = Bgn; Bgn = t1;
        ushort* t2 = Buc; Buc = Bun; Bun = t2;
    }

    // epilogue: silu(g)*u -> h_t (bf16, tiled k-inner-8 for stage B's A-operand)
    int rbase = wm + ((lane >> 4) << 2);
    int cbase = wn + (lane & 15);
    size_t tbase = (size_t)stile * 32 * 8192;
#pragma unroll
    for (int sm_ = 0; sm_ < 4; sm_++) {
#pragma unroll
        for (int r = 0; r < 4; r++) {
            int pos = m0 + rbase + sm_ * 16 + r;
            if (pos < ne) {
                int row = pos & 127;
#pragma unroll
                for (int sn = 0; sn < 4; sn++) {
                    int col = n0 + cbase + sn * 16;
                    float g = accg[sm_][sn][r] + bg[e * D_FF + col];
                    float u = accu[sm_][sn][r] + bu[e * D_FF + col];
                    float hv = (g / (1.f + expf(-g))) * u;
                    int ktb = col >> 6, kb = (col >> 3) & 7, ko = col & 7;
                    h_t[tbase + (size_t)ktb * 8192 + (kb * 128 + row) * 8 + ko] = f2bf(hv);
                }
            }
        }
    }
}

// ---------------- stage B: outp = h @ Wd + bd — 64x128 tiles, 640 blocks (R13) ----------------
__global__ __launch_bounds__(256, 2) void k_expert_down(
    const ushort* __restrict__ Wdt, const float* __restrict__ bd,
    const ushort* __restrict__ h_t, const int* __restrict__ cnt,
    const int* __restrict__ abase, const int* __restrict__ tile64,
    float* __restrict__ outp)
{
    int ti = tile64[blockIdx.x];
    if (ti < 0) return;
    int e = ti >> 16, m0 = ti & 0xffff;       // m0 multiple of 64
    int ne = cnt[e];
    int nt = blockIdx.y;                      // 0..7
    int n0 = nt * 128;
    int stile = (abase[e] >> 7) + (m0 >> 7);
    int hoff = (m0 & 64) ? 1024 : 0;          // byte offset of row-half in each kb block

    __shared__ __align__(16) ushort As8[4096];        // [kb 0..7][row 0..63][ko 0..7] (8KB)
    __shared__ __align__(16) ushort Bd_s[8192];       // k-inner-8 image (16KB)

    int tid = threadIdx.x;
    int lane = tid & 63, wave = tid >> 6;
    int wm = (wave & 1) * 32, wn = (wave >> 1) * 64;

    const char* hbase = (const char*)(h_t + (size_t)stile * 32 * 8192);
    const char* dbase = (const char*)(Wdt + (size_t)(e * 8 + nt) * 32 * 8192);
    int goff = tid * 16;
    int loff = (tid >> 6) * 1024;

    f32x4 acc[2][4];
#pragma unroll
    for (int i = 0; i < 2; i++)
#pragma unroll
        for (int j = 0; j < 4; j++) acc[i][j] = (f32x4){0.f, 0.f, 0.f, 0.f};

    for (int kt = 0; kt < D_FF / 64; kt++) {
        __syncthreads();
        // A: 8KB (64 rows x 64 k), 2 chunks/thread; chunk c -> kb = c>>6, row = c&63
#pragma unroll
        for (int q = 0; q < 2; q++) {
            int c = q * 256 + tid;
            int kb = c >> 6;
            glds16(hbase + kt * 16384 + kb * 2048 + hoff + (c & 63) * 16,
                   (char*)As8 + q * 4096 + loff);
        }
        // B: 16KB
        const char* bsrc = dbase + kt * 16384;
#pragma unroll
        for (int q = 0; q < 4; q++)
            glds16(bsrc + q * 4096 + goff, (char*)Bd_s + q * 4096 + loff);
        __syncthreads();
#pragma unroll
        for (int ks = 0; ks < 2; ks++) {
            int kb = ks * 4 + (lane >> 4);
            int arow_l = wm + (lane & 15);
            bf16x8 af[2];
#pragma unroll
            for (int sm_ = 0; sm_ < 2; sm_++)
                af[sm_] = *(const bf16x8*)&As8[(kb * 64 + arow_l + sm_ * 16) * 8];
#pragma unroll
            for (int sn = 0; sn < 4; sn++) {
                int ncol = wn + sn * 16 + (lane & 15);
                bf16x8 bdf = *(const bf16x8*)&Bd_s[(kb * 128 + ncol) * 8];
#pragma unroll
                for (int sm_ = 0; sm_ < 2; sm_++)
                    acc[sm_][sn] = __builtin_amdgcn_mfma_f32_16x16x32_bf16(af[sm_], bdf, acc[sm_][sn], 0, 0, 0);
            }
        }
    }
    int rbase = wm + ((lane >> 4) << 2);
    int cbase = wn + (lane & 15);
#pragma unroll
    for (int sm_ = 0; sm_ < 2; sm_++) {
#pragma unroll
        for (int r = 0; r < 4; r++) {
            int pos = m0 + rbase + sm_ * 16 + r;
            if (pos < ne) {
                size_t ob = (size_t)(abase[e] + pos) * D_MODEL;
#pragma unroll
                for (int sn = 0; sn < 4; sn++) {
                    int col = n0 + cbase + sn * 16;
                    outp[ob + col] = acc[sm_][sn][r] + bd[e * D_MODEL + col];
                }
            }
        }
    }
}

// ---------------- combine: y[t] = w0*outp[slot0] + w1*outp[slot1] ----------------
__global__ void k_combine(const float* __restrict__ outp, const int* __restrict__ slotpk,
                          const float* __restrict__ wtok, const int* __restrict__ abase,
                          float* __restrict__ y)
{
    int idx = blockIdx.x * 256 + threadIdx.x;   // 524288 float4s
    int t = idx >> 8, j = idx & 255;
    int sp0 = slotpk[t * 2 + 0], sp1 = slotpk[t * 2 + 1];
    float w0 = wtok[t * 2 + 0], w1 = wtok[t * 2 + 1];
    size_t s0 = (size_t)abase[sp0 >> 16] + (sp0 & 0xffff);
    size_t s1 = (size_t)abase[sp1 >> 16] + (sp1 & 0xffff);
    float4 a = ((const float4*)outp)[s0 * (D_MODEL / 4) + j];
    float4 b = ((const float4*)outp)[s1 * (D_MODEL / 4) + j];
    float4 o;
    o.x = w0 * a.x + w1 * b.x;
    o.y = w0 * a.y + w1 * b.y;
    o.z = w0 * a.z + w1 * b.z;
    o.w = w0 * a.w + w1 * b.w;
    ((float4*)y)[idx] = o;
}

extern "C" void kernel_launch(void* const* d_in, const int* in_sizes, int n_in,
                              void* d_out, int out_size, void* d_ws, size_t ws_size,
                              hipStream_t stream)
{
    const float* x  = (const float*)d_in[0];
    const float* gw = (const float*)d_in[1];
    const float* gb = (const float*)d_in[2];
    const float* Wg = (const float*)d_in[3];
    const float* bg = (const float*)d_in[4];
    const float* Wu = (const float*)d_in[5];
    const float* bu = (const float*)d_in[6];
    const float* Wd = (const float*)d_in[7];
    const float* bd = (const float*)d_in[8];
    float* y = (float*)d_out;
    float* loss_out = y + (size_t)T_TOK * D_MODEL;

    char* ws = (char*)d_ws;
    int*    cnt     = (int*)(ws + 0);             // 8 ints   [zeroed]
    float*  probsum = (float*)(ws + 128);         // 8 floats [zeroed]
    int*    abase   = (int*)(ws + 256);           // 8 ints
    int*    tiletab = (int*)(ws + 320);           // MAXTILES ints (ends 480)
    int*    slotpk  = (int*)(ws + 512);           // 4096 ints
    float*  wtok    = (float*)(ws + 16896);       // 4096 floats
    int*    tok     = (int*)(ws + 33280);         // 8*2048 ints (ends 98816)
    int*    tile64  = (int*)(ws + 98816);         // MAXT64 ints (ends 99136)
    ushort* xb      = (ushort*)(ws + 131072);     // 2M bf16 = 4 MB
    ushort* Wgt     = (ushort*)(ws + 4325376);    // 33.55 MB tiled bf16
    ushort* Wut     = (ushort*)(ws + 37879808);   // 33.55 MB
    ushort* Wdt     = (ushort*)(ws + 71434240);   // 33.55 MB
    ushort* h_t     = (ushort*)(ws + 104988672);  // 20.97 MB
    float*  outp    = (float*)(ws + 125960192);   // 20.97 MB
    // total ws use: ~147 MB

    (void)hipMemsetAsync(d_ws, 0, 256, stream);
    // launch 1: router (64 blocks) overlapped with Wg/Wu prep (2048 blocks)
    k_router_prep<<<dim3(64 + 2048), dim3(256), 0, stream>>>(
        x, gw, gb, cnt, probsum, tok, slotpk, wtok, xb, Wg, Wu, Wgt, Wut);
    k_base_loss<<<dim3(1), dim3(64), 0, stream>>>(cnt, probsum, abase, tiletab, tile64, loss_out);
    // launch 3: counted-vmcnt gu GEMM (640 blocks) overlapped with Wd prep (1024 blocks)
    k_gu_prepwd<<<dim3(MAXTILES * 16 + 1024), dim3(256), 0, stream>>>(
        Wgt, Wut, bg, bu, xb, cnt, abase, tiletab, tok, h_t, Wd, Wdt);
    // launch 4: down GEMM, 64-row tiles (640 blocks)
    k_expert_down<<<dim3(MAXT64, 8), dim3(256), 0, stream>>>(
        Wdt, bd, h_t, cnt, abase, tile64, outp);
    k_combine<<<dim3(2048), dim3(256), 0, stream>>>(outp, slotpk, wtok, abase, y);
}